// Round 5
// baseline (379.813 us; speedup 1.0000x reference)
//
#include <hip/hip_runtime.h>

// Problem constants
#define NB 2
#define CC 512
#define NN 2304
#define NH 8
#define DD 16
#define TT 128          // NH*DD
#define O3 384          // 3*TT

typedef __attribute__((ext_vector_type(4))) float f32x4;
typedef __attribute__((ext_vector_type(8))) __bf16 bf16x8;
typedef __attribute__((ext_vector_type(4))) __bf16 bf16x4;
typedef __attribute__((ext_vector_type(4))) _Float16 f16x4;

// ---------------------------------------------------------------------------
// Kernel 0: convert x [b,c,n] fp32 -> xT [b,n,c] bf16 (LDS tile transpose),
//           plus straight fp32->bf16 conversion of w_qkv and w_out.
// ---------------------------------------------------------------------------
__global__ __launch_bounds__(256) void k0_convert(
    const float* __restrict__ x, const float* __restrict__ wqkv,
    const float* __restrict__ wout,
    __bf16* __restrict__ xT, __bf16* __restrict__ wqb, __bf16* __restrict__ wob)
{
    int bid = blockIdx.x;
    int t = threadIdx.x;
    if (bid < 576) {
        __shared__ float tile[64][65];
        int b = bid / 288, rem = bid % 288;
        int nt = rem / 8, cb = rem % 8;
        int n0 = nt * 64, c0 = cb * 64;
        int tc = t >> 6, tn = t & 63;
#pragma unroll
        for (int i = 0; i < 16; i++) {
            int cl = i * 4 + tc;
            tile[cl][tn] = x[(size_t)(b * CC + c0 + cl) * NN + n0 + tn];
        }
        __syncthreads();
#pragma unroll
        for (int i = 0; i < 16; i++) {
            int nl = i * 4 + tc;
            xT[(size_t)(b * NN + n0 + nl) * CC + c0 + tn] = (__bf16)tile[tn][nl];
        }
    } else {
        int wid = bid - 576;
        int base = wid * 256 + t;
#pragma unroll
        for (int i = 0; i < 16; i++) {
            int j = base + i * 16384;           // covers 262144 = 384*512 + 512*128
            if (j < O3 * CC) wqb[j] = (__bf16)wqkv[j];
            else             wob[j - O3 * CC] = (__bf16)wout[j - O3 * CC];
        }
    }
}

// ---------------------------------------------------------------------------
// Kernel 1: QKV GEMM  qkvT[n,o] = sum_c xT[n,c] * W[o,c]  (per batch),
//           fused per-head L2 norm of q,k.  Outputs (fp16 for k2's f16 MFMA):
//           Q,K: [bh][n][16] f16 ;  VT: [bh][16][n] f16
// ---------------------------------------------------------------------------
__global__ __launch_bounds__(256) void k1_qkv(
    const __bf16* __restrict__ xT, const __bf16* __restrict__ wqb,
    _Float16* __restrict__ Q, _Float16* __restrict__ K, _Float16* __restrict__ VT)
{
    int ob = blockIdx.x, nt = blockIdx.y, b = blockIdx.z;
    int lane = threadIdx.x & 63, wave = threadIdx.x >> 6;
    int quad = lane >> 4, col = lane & 15;
    int n0 = nt * 64 + wave * 16;
    int o0 = ob * 32;

    f32x4 acc[2];
    acc[0] = (f32x4){0.f, 0.f, 0.f, 0.f};
    acc[1] = (f32x4){0.f, 0.f, 0.f, 0.f};

    const __bf16* arow = xT + (size_t)(b * NN + n0 + col) * CC + quad * 8;
    const __bf16* brow0 = wqb + (size_t)(o0 + col) * CC + quad * 8;
    const __bf16* brow1 = brow0 + 16 * CC;

    bf16x8 a  = *(const bf16x8*)(arow);
    bf16x8 w0 = *(const bf16x8*)(brow0);
    bf16x8 w1 = *(const bf16x8*)(brow1);
#pragma unroll
    for (int ks = 0; ks < 16; ks++) {
        bf16x8 an, wn0, wn1;
        if (ks < 15) {
            an  = *(const bf16x8*)(arow + (ks + 1) * 32);
            wn0 = *(const bf16x8*)(brow0 + (ks + 1) * 32);
            wn1 = *(const bf16x8*)(brow1 + (ks + 1) * 32);
        }
        acc[0] = __builtin_amdgcn_mfma_f32_16x16x32_bf16(a, w0, acc[0], 0, 0, 0);
        acc[1] = __builtin_amdgcn_mfma_f32_16x16x32_bf16(a, w1, acc[1], 0, 0, 0);
        a = an; w0 = wn0; w1 = wn1;
    }

#pragma unroll
    for (int s = 0; s < 2; s++) {
        int oc = o0 + s * 16 + col;
        int d = oc & 15, h = (oc >> 4) & 7, kind = oc >> 7;  // 0=q 1=k 2=v
        f32x4 v = acc[s];
        if (kind < 2) {
            float ss0 = v[0] * v[0], ss1 = v[1] * v[1], ss2 = v[2] * v[2], ss3 = v[3] * v[3];
#pragma unroll
            for (int m = 1; m < 16; m <<= 1) {
                ss0 += __shfl_xor(ss0, m);
                ss1 += __shfl_xor(ss1, m);
                ss2 += __shfl_xor(ss2, m);
                ss3 += __shfl_xor(ss3, m);
            }
            v[0] *= 1.0f / fmaxf(sqrtf(ss0), 1e-12f);
            v[1] *= 1.0f / fmaxf(sqrtf(ss1), 1e-12f);
            v[2] *= 1.0f / fmaxf(sqrtf(ss2), 1e-12f);
            v[3] *= 1.0f / fmaxf(sqrtf(ss3), 1e-12f);
            _Float16* dst = (kind == 0 ? Q : K) + (size_t)(b * NH + h) * NN * DD;
#pragma unroll
            for (int r = 0; r < 4; r++) {
                int n = n0 + quad * 4 + r;
                dst[(size_t)n * DD + d] = (_Float16)v[r];
            }
        } else {
            f16x4 pk;
#pragma unroll
            for (int r = 0; r < 4; r++) pk[r] = (_Float16)v[r];
            int n = n0 + quad * 4;
            *(f16x4*)(VT + (size_t)((b * NH + h) * DD + d) * NN + n) = pk;
        }
    }
}

// ---------------------------------------------------------------------------
// Kernel 2: attention — TRANSPOSE-FREE flash via K=16 MFMAs.
//   S^T = mfma_16x16x16_f16(A=K-frag, B=Q-frag): C-layout lane(quad,col)
//   holds S^T[key=quad*4+r][q=col]. exp2 in place. Those same 4 regs ARE a
//   valid B-operand (B[k=key=quad*4+j][n=q=col]) for
//   O^T += mfma_16x16x16_f16(A=V^T-frag, B=P-frag).
//   -> zero LDS, zero shuffles, zero waitcnt stalls in the K-loop.
// Split-K over keys (2 x 1152); purely additive combine (no max-subtraction
// needed since |logit| <= temp). Denominator: 8 VALU adds/iter + 2 shuffles.
// Outputs: Opart[sp][bh][d][n] fp32 ; Lpart[sp][bh][n] fp32
// ---------------------------------------------------------------------------
__global__ __launch_bounds__(256) void k2_attn(
    const _Float16* __restrict__ Q, const _Float16* __restrict__ K,
    const _Float16* __restrict__ VT, const float* __restrict__ temp,
    float* __restrict__ Opart, float* __restrict__ Lpart)
{
    int qt = blockIdx.x, bh = blockIdx.y, sp = blockIdx.z;
    int lane = threadIdx.x & 63, wave = threadIdx.x >> 6;
    int quad = lane >> 4, col = lane & 15;
    int kbase = sp * (NN / 2);   // 1152 keys per split = 72 chunks of 16

    const _Float16* Qb = Q + (size_t)bh * NN * DD;
    const _Float16* Kb = K + (size_t)bh * NN * DD;
    const _Float16* Vb = VT + (size_t)bh * DD * NN;
    float tl2 = temp[bh & 7] * 1.4426950408889634f;   // exp(x)=2^(x*log2e)

    // Q B-fragment (held for whole kernel): Q[q=qrow][d=quad*4..+3]
    int qrow = qt * 64 + wave * 16 + col;
    f16x4 qf = *(const f16x4*)(Qb + (size_t)qrow * DD + quad * 4);

    f32x4 o_acc = {0.f, 0.f, 0.f, 0.f};
    float l_acc = 0.f;
    const f32x4 zc = {0.f, 0.f, 0.f, 0.f};

    // Double-buffered 2-chunk (32-key) iterations, prefetched 2 iters ahead.
    // K A-frag chunk c: K[key=c*16+col][d=quad*4..+3]      (coalesced 8B)
    // V A-frag chunk c: VT[d=col][key=c*16+quad*4..+3]     (8B per lane)
    f16x4 kb[2][2], vb[2][2];
#pragma unroll
    for (int i = 0; i < 2; i++)
#pragma unroll
        for (int c = 0; c < 2; c++) {
            int ch = kbase + (i * 2 + c) * 16;
            kb[i][c] = *(const f16x4*)(Kb + (size_t)(ch + col) * DD + quad * 4);
            vb[i][c] = *(const f16x4*)(Vb + (size_t)col * NN + ch + quad * 4);
        }

    for (int it = 0; it < 36; ++it) {
        int cur = it & 1;
#pragma unroll
        for (int c = 0; c < 2; ++c) {
            f32x4 st = __builtin_amdgcn_mfma_f32_16x16x16f16(kb[cur][c], qf, zc, 0, 0, 0);
            f16x4 pf;
#pragma unroll
            for (int r = 0; r < 4; ++r) {
                float p = __builtin_amdgcn_exp2f(tl2 * st[r]);
                pf[r] = (_Float16)p;
                l_acc += p;   // f16 rounding error ~2^-12 relative: negligible
            }
            o_acc = __builtin_amdgcn_mfma_f32_16x16x16f16(vb[cur][c], pf, o_acc, 0, 0, 0);
        }
        if (it < 34) {
            int base2 = kbase + (it + 2) * 32;
#pragma unroll
            for (int c = 0; c < 2; ++c) {
                int ch = base2 + c * 16;
                kb[cur][c] = *(const f16x4*)(Kb + (size_t)(ch + col) * DD + quad * 4);
                vb[cur][c] = *(const f16x4*)(Vb + (size_t)col * NN + ch + quad * 4);
            }
        }
    }

    // lane(quad,col) has partial l over its keys; sum across quads -> l[q=col]
    l_acc += __shfl_xor(l_acc, 16);
    l_acc += __shfl_xor(l_acc, 32);

    // O^T[d=quad*4+r][q=col] -> Opart[sp*16+bh][d][n]
    float* Ob = Opart + ((size_t)((sp * 16 + bh) * DD) + quad * 4) * NN
              + (size_t)qt * 64 + wave * 16 + col;
#pragma unroll
    for (int r = 0; r < 4; ++r) Ob[(size_t)r * NN] = o_acc[r];
    if (lane < 16)
        Lpart[(size_t)(sp * 16 + bh) * NN + qt * 64 + wave * 16 + col] = l_acc;
}

// ---------------------------------------------------------------------------
// Kernel 2c: additive combine of the 2 key-splits + divide, write AO.
// AO: [b][n][t=h*16+d] bf16. One thread per (bh, n).
// ---------------------------------------------------------------------------
__global__ __launch_bounds__(256) void k2c_combine(
    const float* __restrict__ Opart, const float* __restrict__ Lpart,
    __bf16* __restrict__ AO)
{
    int gid = blockIdx.x * 256 + threadIdx.x;   // 0..36863
    int bh = gid / NN, n = gid % NN;
    int b = bh >> 3, h = bh & 7;
    const float* O0 = Opart + (size_t)bh * DD * NN + n;
    const float* O1 = Opart + (size_t)(16 + bh) * DD * NN + n;
    float l = Lpart[(size_t)bh * NN + n] + Lpart[(size_t)(16 + bh) * NN + n];
    float inv = 1.0f / l;
    bf16x8 v0, v1;
#pragma unroll
    for (int d = 0; d < 8; d++)
        v0[d] = (__bf16)((O0[(size_t)d * NN] + O1[(size_t)d * NN]) * inv);
#pragma unroll
    for (int d = 8; d < 16; d++)
        v1[d - 8] = (__bf16)((O0[(size_t)d * NN] + O1[(size_t)d * NN]) * inv);
    __bf16* dst = AO + (size_t)b * NN * TT + (size_t)n * TT + h * DD;
    *(bf16x8*)dst = v0;
    *(bf16x8*)(dst + 8) = v1;
}

// ---------------------------------------------------------------------------
// Kernel 3: projection  out[b,c,n] = sum_t w_out[c,t] * AO[b,n,t]  (pre-BN fp32
// straight into d_out). c-slab 32 per wave: grid (16,36,2)=1152 blocks.
// ---------------------------------------------------------------------------
__global__ __launch_bounds__(256) void k3_proj(
    const __bf16* __restrict__ AO, const __bf16* __restrict__ wob,
    float* __restrict__ out)
{
    int cb = blockIdx.x, nt = blockIdx.y, b = blockIdx.z;
    int lane = threadIdx.x & 63, wave = threadIdx.x >> 6;
    int quad = lane >> 4, col = lane & 15;
    int n0 = nt * 64 + wave * 16, c0 = cb * 32;

    f32x4 acc[2];
    acc[0] = (f32x4){0.f, 0.f, 0.f, 0.f};
    acc[1] = (f32x4){0.f, 0.f, 0.f, 0.f};

    const __bf16* ab = AO + (size_t)(b * NN + n0 + col) * TT + quad * 8;
    const __bf16* wb0 = wob + (size_t)(c0 + col) * TT + quad * 8;
    const __bf16* wb1 = wb0 + 16 * TT;
#pragma unroll
    for (int ks = 0; ks < 4; ks++) {
        bf16x8 a  = *(const bf16x8*)(ab + ks * 32);
        bf16x8 w0 = *(const bf16x8*)(wb0 + ks * 32);
        bf16x8 w1 = *(const bf16x8*)(wb1 + ks * 32);
        acc[0] = __builtin_amdgcn_mfma_f32_16x16x32_bf16(a, w0, acc[0], 0, 0, 0);
        acc[1] = __builtin_amdgcn_mfma_f32_16x16x32_bf16(a, w1, acc[1], 0, 0, 0);
    }
#pragma unroll
    for (int s = 0; s < 2; s++) {
        int c = c0 + s * 16 + col;
        float* dst = out + (size_t)(b * CC + c) * NN + n0 + quad * 4;
        *(f32x4*)dst = acc[s];
    }
}

// ---------------------------------------------------------------------------
// Kernel 4: training-mode BatchNorm, in place on d_out. One block per channel.
// ---------------------------------------------------------------------------
__global__ __launch_bounds__(256) void k4_bn(
    float* __restrict__ out, const float* __restrict__ gamma,
    const float* __restrict__ beta)
{
    int c = blockIdx.x;
    int t = threadIdx.x;
    float vals[18];
    float s = 0.f, q = 0.f;
#pragma unroll
    for (int i = 0; i < 18; i++) {
        int j = i * 256 + t;          // 0..4607 over (b,n)
        int b = j / NN, n = j % NN;
        float v = out[(size_t)(b * CC + c) * NN + n];
        vals[i] = v; s += v; q += v * v;
    }
#pragma unroll
    for (int m = 1; m < 64; m <<= 1) { s += __shfl_xor(s, m); q += __shfl_xor(q, m); }
    __shared__ float rs[4], rq[4];
    int lane = t & 63, wave = t >> 6;
    if (lane == 0) { rs[wave] = s; rq[wave] = q; }
    __syncthreads();
    s = rs[0] + rs[1] + rs[2] + rs[3];
    q = rq[0] + rq[1] + rq[2] + rq[3];
    float mean = s * (1.0f / 4608.0f);
    float var = q * (1.0f / 4608.0f) - mean * mean;
    float sc = rsqrtf(var + 1e-5f) * gamma[c];
    float sh = beta[c] - mean * sc;
#pragma unroll
    for (int i = 0; i < 18; i++) {
        int j = i * 256 + t;
        int b = j / NN, n = j % NN;
        out[(size_t)(b * CC + c) * NN + n] = vals[i] * sc + sh;
    }
}

// ---------------------------------------------------------------------------
extern "C" void kernel_launch(void* const* d_in, const int* in_sizes, int n_in,
                              void* d_out, int out_size, void* d_ws, size_t ws_size,
                              hipStream_t stream) {
    const float* x     = (const float*)d_in[0];
    const float* wqkv  = (const float*)d_in[1];
    const float* temp  = (const float*)d_in[2];
    const float* wout  = (const float*)d_in[3];
    const float* gamma = (const float*)d_in[4];
    const float* beta  = (const float*)d_in[5];
    float* out = (float*)d_out;

    char* ws = (char*)d_ws;
    // workspace layout (bytes). xT/wqb are DEAD after k1 -> their region
    // [0, 5,111,808) is reused for the k2 split-K partials (stream-ordered).
    const size_t OFF_XT = 0;                 // 2*2304*512*2   = 4,718,592
    const size_t OFF_WQ = 4718592;           // 384*512*2      =   393,216
    const size_t OFF_WO = 5111808;           // 512*128*2      =   131,072
    const size_t OFF_Q  = 5242880;           // 2*8*2304*16*2  = 1,179,648
    const size_t OFF_K  = 6422528;
    const size_t OFF_VT = 7602176;
    const size_t OFF_AO = 8781824;           // 2*2304*128*2   = 1,179,648 -> end 9,961,472
    const size_t OFF_OP = 0;                 // 2*16*16*2304*4 = 4,718,592 (aliases xT)
    const size_t OFF_LP = 4718592;           // 2*16*2304*4    =   294,912 (aliases wqb)

    __bf16* xT  = (__bf16*)(ws + OFF_XT);
    __bf16* wqb = (__bf16*)(ws + OFF_WQ);
    __bf16* wob = (__bf16*)(ws + OFF_WO);
    _Float16* Q  = (_Float16*)(ws + OFF_Q);
    _Float16* K  = (_Float16*)(ws + OFF_K);
    _Float16* VT = (_Float16*)(ws + OFF_VT);
    __bf16* AO  = (__bf16*)(ws + OFF_AO);
    float* Opart = (float*)(ws + OFF_OP);
    float* Lpart = (float*)(ws + OFF_LP);

    k0_convert<<<640, 256, 0, stream>>>(x, wqkv, wout, xT, wqb, wob);
    k1_qkv<<<dim3(12, 36, 2), 256, 0, stream>>>(xT, wqb, Q, K, VT);
    k2_attn<<<dim3(36, 16, 2), 256, 0, stream>>>(Q, K, VT, temp, Opart, Lpart);
    k2c_combine<<<144, 256, 0, stream>>>(Opart, Lpart, AO);
    k3_proj<<<dim3(16, 36, 2), 256, 0, stream>>>(AO, wob, out);
    k4_bn<<<512, 256, 0, stream>>>(out, gamma, beta);
}

// Round 6
// 171.779 us; speedup vs baseline: 2.2111x; 2.2111x over previous
//
#include <hip/hip_runtime.h>

// Problem constants
#define NB 2
#define CC 512
#define NN 2304
#define NH 8
#define DD 16
#define TT 128          // NH*DD
#define O3 384          // 3*TT

typedef __attribute__((ext_vector_type(4))) float f32x4;
typedef __attribute__((ext_vector_type(8))) __bf16 bf16x8;
typedef __attribute__((ext_vector_type(4))) __bf16 bf16x4;
typedef __attribute__((ext_vector_type(4))) _Float16 f16x4;

// ---------------------------------------------------------------------------
// Kernel 0: convert x [b,c,n] fp32 -> xT [b,n,c] bf16 (LDS tile transpose),
//           plus straight fp32->bf16 conversion of w_qkv and w_out.
// ---------------------------------------------------------------------------
__global__ __launch_bounds__(256) void k0_convert(
    const float* __restrict__ x, const float* __restrict__ wqkv,
    const float* __restrict__ wout,
    __bf16* __restrict__ xT, __bf16* __restrict__ wqb, __bf16* __restrict__ wob)
{
    int bid = blockIdx.x;
    int t = threadIdx.x;
    if (bid < 576) {
        __shared__ float tile[64][65];
        int b = bid / 288, rem = bid % 288;
        int nt = rem / 8, cb = rem % 8;
        int n0 = nt * 64, c0 = cb * 64;
        int tc = t >> 6, tn = t & 63;
#pragma unroll
        for (int i = 0; i < 16; i++) {
            int cl = i * 4 + tc;
            tile[cl][tn] = x[(size_t)(b * CC + c0 + cl) * NN + n0 + tn];
        }
        __syncthreads();
#pragma unroll
        for (int i = 0; i < 16; i++) {
            int nl = i * 4 + tc;
            xT[(size_t)(b * NN + n0 + nl) * CC + c0 + tn] = (__bf16)tile[tn][nl];
        }
    } else {
        int wid = bid - 576;
        int base = wid * 256 + t;
#pragma unroll
        for (int i = 0; i < 16; i++) {
            int j = base + i * 16384;           // covers 262144 = 384*512 + 512*128
            if (j < O3 * CC) wqb[j] = (__bf16)wqkv[j];
            else             wob[j - O3 * CC] = (__bf16)wout[j - O3 * CC];
        }
    }
}

// ---------------------------------------------------------------------------
// Kernel 1: QKV GEMM  qkvT[n,o] = sum_c xT[n,c] * W[o,c]  (per batch),
//           fused per-head L2 norm of q,k.  Outputs (fp16 for k2's f16 MFMA):
//           Q,K: [bh][n][16] f16 ;  VT: [bh][16][n] f16
// ---------------------------------------------------------------------------
__global__ __launch_bounds__(256) void k1_qkv(
    const __bf16* __restrict__ xT, const __bf16* __restrict__ wqb,
    _Float16* __restrict__ Q, _Float16* __restrict__ K, _Float16* __restrict__ VT)
{
    int ob = blockIdx.x, nt = blockIdx.y, b = blockIdx.z;
    int lane = threadIdx.x & 63, wave = threadIdx.x >> 6;
    int quad = lane >> 4, col = lane & 15;
    int n0 = nt * 64 + wave * 16;
    int o0 = ob * 32;

    f32x4 acc[2];
    acc[0] = (f32x4){0.f, 0.f, 0.f, 0.f};
    acc[1] = (f32x4){0.f, 0.f, 0.f, 0.f};

    const __bf16* arow = xT + (size_t)(b * NN + n0 + col) * CC + quad * 8;
    const __bf16* brow0 = wqb + (size_t)(o0 + col) * CC + quad * 8;
    const __bf16* brow1 = brow0 + 16 * CC;

    bf16x8 a  = *(const bf16x8*)(arow);
    bf16x8 w0 = *(const bf16x8*)(brow0);
    bf16x8 w1 = *(const bf16x8*)(brow1);
#pragma unroll
    for (int ks = 0; ks < 16; ks++) {
        bf16x8 an, wn0, wn1;
        if (ks < 15) {
            an  = *(const bf16x8*)(arow + (ks + 1) * 32);
            wn0 = *(const bf16x8*)(brow0 + (ks + 1) * 32);
            wn1 = *(const bf16x8*)(brow1 + (ks + 1) * 32);
        }
        acc[0] = __builtin_amdgcn_mfma_f32_16x16x32_bf16(a, w0, acc[0], 0, 0, 0);
        acc[1] = __builtin_amdgcn_mfma_f32_16x16x32_bf16(a, w1, acc[1], 0, 0, 0);
        a = an; w0 = wn0; w1 = wn1;
    }

#pragma unroll
    for (int s = 0; s < 2; s++) {
        int oc = o0 + s * 16 + col;
        int d = oc & 15, h = (oc >> 4) & 7, kind = oc >> 7;  // 0=q 1=k 2=v
        f32x4 v = acc[s];
        if (kind < 2) {
            float ss0 = v[0] * v[0], ss1 = v[1] * v[1], ss2 = v[2] * v[2], ss3 = v[3] * v[3];
#pragma unroll
            for (int m = 1; m < 16; m <<= 1) {
                ss0 += __shfl_xor(ss0, m);
                ss1 += __shfl_xor(ss1, m);
                ss2 += __shfl_xor(ss2, m);
                ss3 += __shfl_xor(ss3, m);
            }
            v[0] *= 1.0f / fmaxf(sqrtf(ss0), 1e-12f);
            v[1] *= 1.0f / fmaxf(sqrtf(ss1), 1e-12f);
            v[2] *= 1.0f / fmaxf(sqrtf(ss2), 1e-12f);
            v[3] *= 1.0f / fmaxf(sqrtf(ss3), 1e-12f);
            _Float16* dst = (kind == 0 ? Q : K) + (size_t)(b * NH + h) * NN * DD;
#pragma unroll
            for (int r = 0; r < 4; r++) {
                int n = n0 + quad * 4 + r;
                dst[(size_t)n * DD + d] = (_Float16)v[r];
            }
        } else {
            f16x4 pk;
#pragma unroll
            for (int r = 0; r < 4; r++) pk[r] = (_Float16)v[r];
            int n = n0 + quad * 4;
            *(f16x4*)(VT + (size_t)((b * NH + h) * DD + d) * NN + n) = pk;
        }
    }
}

// ---------------------------------------------------------------------------
// Kernel 2: attention — TRANSPOSE-FREE flash via K=16 MFMAs.
//   S^T = mfma_16x16x16_f16(A=K-frag, B=Q-frag): C-layout lane(quad,col)
//   holds S^T[key=quad*4+r][q=col]. exp2 in place; those same regs ARE a
//   valid B-operand for O^T += mfma_16x16x16_f16(A=V^T-frag, B=P-frag).
//   Zero LDS / shuffles / waitcnt stalls in the K-loop.
// ROUND-6 FIX: round 5 indexed the prefetch arrays with a RUNTIME value
// (it&1) -> compiler demoted them to scratch (VGPR 40, VALUBusy 66%,
// 279us). All fragments are now NAMED registers, compile-time only.
// Outputs: Opart[sp][bh][d][n] fp32 ; Lpart[sp][bh][n] fp32
// ---------------------------------------------------------------------------
__global__ __launch_bounds__(256) void k2_attn(
    const _Float16* __restrict__ Q, const _Float16* __restrict__ K,
    const _Float16* __restrict__ VT, const float* __restrict__ temp,
    float* __restrict__ Opart, float* __restrict__ Lpart)
{
    int qt = blockIdx.x, bh = blockIdx.y, sp = blockIdx.z;
    int lane = threadIdx.x & 63, wave = threadIdx.x >> 6;
    int quad = lane >> 4, col = lane & 15;
    int kbase = sp * (NN / 2);   // 1152 keys per split = 18 iters of 64

    const _Float16* Qb = Q + (size_t)bh * NN * DD;
    float tl2 = temp[bh & 7] * 1.4426950408889634f;   // exp(x)=2^(x*log2e)

    // Q B-fragment (held for whole kernel): Q[q=qrow][d=quad*4..+3]
    int qrow = qt * 64 + wave * 16 + col;
    f16x4 qf = *(const f16x4*)(Qb + (size_t)qrow * DD + quad * 4);

    f32x4 o_acc = {0.f, 0.f, 0.f, 0.f};
    float l_acc = 0.f;
    const f32x4 zc = {0.f, 0.f, 0.f, 0.f};

    // K A-frag chunk: K[key=ch+col][d=quad*4..+3]   (contiguous 512B/wave)
    // V A-frag chunk: VT[d=col][key=ch+quad*4..+3]  (16 rows x 32B)
    const _Float16* kp = K + (size_t)bh * NN * DD + ((size_t)(kbase + col)) * DD + quad * 4;
    const _Float16* vp = VT + (size_t)bh * DD * NN + (size_t)col * NN + kbase + quad * 4;

    f16x4 kf0 = *(const f16x4*)(kp);
    f16x4 kf1 = *(const f16x4*)(kp + 16 * DD);
    f16x4 kf2 = *(const f16x4*)(kp + 32 * DD);
    f16x4 kf3 = *(const f16x4*)(kp + 48 * DD);
    f16x4 vf0 = *(const f16x4*)(vp);
    f16x4 vf1 = *(const f16x4*)(vp + 16);
    f16x4 vf2 = *(const f16x4*)(vp + 32);
    f16x4 vf3 = *(const f16x4*)(vp + 48);

#define K2_CHUNK(KF, VF)                                                        \
    {                                                                           \
        f32x4 st = __builtin_amdgcn_mfma_f32_16x16x16f16(KF, qf, zc, 0, 0, 0);  \
        f16x4 pf;                                                               \
        float p0 = __builtin_amdgcn_exp2f(tl2 * st[0]);                         \
        float p1 = __builtin_amdgcn_exp2f(tl2 * st[1]);                         \
        float p2 = __builtin_amdgcn_exp2f(tl2 * st[2]);                         \
        float p3 = __builtin_amdgcn_exp2f(tl2 * st[3]);                         \
        pf[0] = (_Float16)p0; pf[1] = (_Float16)p1;                             \
        pf[2] = (_Float16)p2; pf[3] = (_Float16)p3;                             \
        l_acc += (p0 + p1) + (p2 + p3);                                         \
        o_acc = __builtin_amdgcn_mfma_f32_16x16x16f16(VF, pf, o_acc, 0, 0, 0);  \
    }

    for (int it = 0; it < 18; ++it) {
        f16x4 kn0, kn1, kn2, kn3, vn0, vn1, vn2, vn3;
        if (it < 17) {
            const _Float16* kq = kp + 64 * DD;
            const _Float16* vq = vp + 64;
            kn0 = *(const f16x4*)(kq);
            kn1 = *(const f16x4*)(kq + 16 * DD);
            kn2 = *(const f16x4*)(kq + 32 * DD);
            kn3 = *(const f16x4*)(kq + 48 * DD);
            vn0 = *(const f16x4*)(vq);
            vn1 = *(const f16x4*)(vq + 16);
            vn2 = *(const f16x4*)(vq + 32);
            vn3 = *(const f16x4*)(vq + 48);
        }
        K2_CHUNK(kf0, vf0)
        K2_CHUNK(kf1, vf1)
        K2_CHUNK(kf2, vf2)
        K2_CHUNK(kf3, vf3)
        kf0 = kn0; kf1 = kn1; kf2 = kn2; kf3 = kn3;
        vf0 = vn0; vf1 = vn1; vf2 = vn2; vf3 = vn3;
        kp += 64 * DD; vp += 64;
    }
#undef K2_CHUNK

    // lane(quad,col) has partial l over its keys; sum across quads -> l[q=col]
    l_acc += __shfl_xor(l_acc, 16);
    l_acc += __shfl_xor(l_acc, 32);

    // O^T[d=quad*4+r][q=col] -> Opart[sp*16+bh][d][n]
    float* Ob = Opart + ((size_t)((sp * 16 + bh) * DD) + quad * 4) * NN
              + (size_t)qt * 64 + wave * 16 + col;
#pragma unroll
    for (int r = 0; r < 4; ++r) Ob[(size_t)r * NN] = o_acc[r];
    if (lane < 16)
        Lpart[(size_t)(sp * 16 + bh) * NN + qt * 64 + wave * 16 + col] = l_acc;
}

// ---------------------------------------------------------------------------
// Kernel 2c: additive combine of the 2 key-splits + divide, write AO.
// AO: [b][n][t=h*16+d] bf16. One thread per (bh, n).
// ---------------------------------------------------------------------------
__global__ __launch_bounds__(256) void k2c_combine(
    const float* __restrict__ Opart, const float* __restrict__ Lpart,
    __bf16* __restrict__ AO)
{
    int gid = blockIdx.x * 256 + threadIdx.x;   // 0..36863
    int bh = gid / NN, n = gid % NN;
    int b = bh >> 3, h = bh & 7;
    const float* O0 = Opart + (size_t)bh * DD * NN + n;
    const float* O1 = Opart + (size_t)(16 + bh) * DD * NN + n;
    float l = Lpart[(size_t)bh * NN + n] + Lpart[(size_t)(16 + bh) * NN + n];
    float inv = 1.0f / l;
    bf16x8 v0, v1;
#pragma unroll
    for (int d = 0; d < 8; d++)
        v0[d] = (__bf16)((O0[(size_t)d * NN] + O1[(size_t)d * NN]) * inv);
#pragma unroll
    for (int d = 8; d < 16; d++)
        v1[d - 8] = (__bf16)((O0[(size_t)d * NN] + O1[(size_t)d * NN]) * inv);
    __bf16* dst = AO + (size_t)b * NN * TT + (size_t)n * TT + h * DD;
    *(bf16x8*)dst = v0;
    *(bf16x8*)(dst + 8) = v1;
}

// ---------------------------------------------------------------------------
// Kernel 3: projection  out[b,c,n] = sum_t w_out[c,t] * AO[b,n,t]  (pre-BN fp32
// straight into d_out). c-slab 32 per wave: grid (16,36,2)=1152 blocks.
// ---------------------------------------------------------------------------
__global__ __launch_bounds__(256) void k3_proj(
    const __bf16* __restrict__ AO, const __bf16* __restrict__ wob,
    float* __restrict__ out)
{
    int cb = blockIdx.x, nt = blockIdx.y, b = blockIdx.z;
    int lane = threadIdx.x & 63, wave = threadIdx.x >> 6;
    int quad = lane >> 4, col = lane & 15;
    int n0 = nt * 64 + wave * 16, c0 = cb * 32;

    f32x4 acc[2];
    acc[0] = (f32x4){0.f, 0.f, 0.f, 0.f};
    acc[1] = (f32x4){0.f, 0.f, 0.f, 0.f};

    const __bf16* ab = AO + (size_t)(b * NN + n0 + col) * TT + quad * 8;
    const __bf16* wb0 = wob + (size_t)(c0 + col) * TT + quad * 8;
    const __bf16* wb1 = wb0 + 16 * TT;
#pragma unroll
    for (int ks = 0; ks < 4; ks++) {
        bf16x8 a  = *(const bf16x8*)(ab + ks * 32);
        bf16x8 w0 = *(const bf16x8*)(wb0 + ks * 32);
        bf16x8 w1 = *(const bf16x8*)(wb1 + ks * 32);
        acc[0] = __builtin_amdgcn_mfma_f32_16x16x32_bf16(a, w0, acc[0], 0, 0, 0);
        acc[1] = __builtin_amdgcn_mfma_f32_16x16x32_bf16(a, w1, acc[1], 0, 0, 0);
    }
#pragma unroll
    for (int s = 0; s < 2; s++) {
        int c = c0 + s * 16 + col;
        float* dst = out + (size_t)(b * CC + c) * NN + n0 + quad * 4;
        *(f32x4*)dst = acc[s];
    }
}

// ---------------------------------------------------------------------------
// Kernel 4: training-mode BatchNorm, in place on d_out. One block per channel.
// ---------------------------------------------------------------------------
__global__ __launch_bounds__(256) void k4_bn(
    float* __restrict__ out, const float* __restrict__ gamma,
    const float* __restrict__ beta)
{
    int c = blockIdx.x;
    int t = threadIdx.x;
    float vals[18];
    float s = 0.f, q = 0.f;
#pragma unroll
    for (int i = 0; i < 18; i++) {
        int j = i * 256 + t;          // 0..4607 over (b,n)
        int b = j / NN, n = j % NN;
        float v = out[(size_t)(b * CC + c) * NN + n];
        vals[i] = v; s += v; q += v * v;
    }
#pragma unroll
    for (int m = 1; m < 64; m <<= 1) { s += __shfl_xor(s, m); q += __shfl_xor(q, m); }
    __shared__ float rs[4], rq[4];
    int lane = t & 63, wave = t >> 6;
    if (lane == 0) { rs[wave] = s; rq[wave] = q; }
    __syncthreads();
    s = rs[0] + rs[1] + rs[2] + rs[3];
    q = rq[0] + rq[1] + rq[2] + rq[3];
    float mean = s * (1.0f / 4608.0f);
    float var = q * (1.0f / 4608.0f) - mean * mean;
    float sc = rsqrtf(var + 1e-5f) * gamma[c];
    float sh = beta[c] - mean * sc;
#pragma unroll
    for (int i = 0; i < 18; i++) {
        int j = i * 256 + t;
        int b = j / NN, n = j % NN;
        out[(size_t)(b * CC + c) * NN + n] = vals[i] * sc + sh;
    }
}

// ---------------------------------------------------------------------------
extern "C" void kernel_launch(void* const* d_in, const int* in_sizes, int n_in,
                              void* d_out, int out_size, void* d_ws, size_t ws_size,
                              hipStream_t stream) {
    const float* x     = (const float*)d_in[0];
    const float* wqkv  = (const float*)d_in[1];
    const float* temp  = (const float*)d_in[2];
    const float* wout  = (const float*)d_in[3];
    const float* gamma = (const float*)d_in[4];
    const float* beta  = (const float*)d_in[5];
    float* out = (float*)d_out;

    char* ws = (char*)d_ws;
    // workspace layout (bytes). xT/wqb are DEAD after k1 -> their region
    // [0, 5,111,808) is reused for the k2 split-K partials (stream-ordered).
    const size_t OFF_XT = 0;                 // 2*2304*512*2   = 4,718,592
    const size_t OFF_WQ = 4718592;           // 384*512*2      =   393,216
    const size_t OFF_WO = 5111808;           // 512*128*2      =   131,072
    const size_t OFF_Q  = 5242880;           // 2*8*2304*16*2  = 1,179,648
    const size_t OFF_K  = 6422528;
    const size_t OFF_VT = 7602176;
    const size_t OFF_AO = 8781824;           // 2*2304*128*2   = 1,179,648 -> end 9,961,472
    const size_t OFF_OP = 0;                 // 2*16*16*2304*4 = 4,718,592 (aliases xT)
    const size_t OFF_LP = 4718592;           // 2*16*2304*4    =   294,912 (aliases wqb)

    __bf16* xT  = (__bf16*)(ws + OFF_XT);
    __bf16* wqb = (__bf16*)(ws + OFF_WQ);
    __bf16* wob = (__bf16*)(ws + OFF_WO);
    _Float16* Q  = (_Float16*)(ws + OFF_Q);
    _Float16* K  = (_Float16*)(ws + OFF_K);
    _Float16* VT = (_Float16*)(ws + OFF_VT);
    __bf16* AO  = (__bf16*)(ws + OFF_AO);
    float* Opart = (float*)(ws + OFF_OP);
    float* Lpart = (float*)(ws + OFF_LP);

    k0_convert<<<640, 256, 0, stream>>>(x, wqkv, wout, xT, wqb, wob);
    k1_qkv<<<dim3(12, 36, 2), 256, 0, stream>>>(xT, wqb, Q, K, VT);
    k2_attn<<<dim3(36, 16, 2), 256, 0, stream>>>(Q, K, VT, temp, Opart, Lpart);
    k2c_combine<<<144, 256, 0, stream>>>(Opart, Lpart, AO);
    k3_proj<<<dim3(16, 36, 2), 256, 0, stream>>>(AO, wob, out);
    k4_bn<<<512, 256, 0, stream>>>(out, gamma, beta);
}

// Round 7
// 150.382 us; speedup vs baseline: 2.5257x; 1.1423x over previous
//
#include <hip/hip_runtime.h>

// Problem constants
#define NB 2
#define CC 512
#define NN 2304
#define NH 8
#define DD 16
#define TT 128          // NH*DD
#define O3 384          // 3*TT

typedef __attribute__((ext_vector_type(4))) float f32x4;
typedef __attribute__((ext_vector_type(8))) __bf16 bf16x8;
typedef __attribute__((ext_vector_type(4))) __bf16 bf16x4;
typedef __attribute__((ext_vector_type(4))) _Float16 f16x4;

// ---------------------------------------------------------------------------
// Kernel 0: convert x [b,c,n] fp32 -> xT [b,n,c] bf16 (LDS tile transpose),
//           plus straight fp32->bf16 conversion of w_qkv and w_out.
// ---------------------------------------------------------------------------
__global__ __launch_bounds__(256) void k0_convert(
    const float* __restrict__ x, const float* __restrict__ wqkv,
    const float* __restrict__ wout,
    __bf16* __restrict__ xT, __bf16* __restrict__ wqb, __bf16* __restrict__ wob)
{
    int bid = blockIdx.x;
    int t = threadIdx.x;
    if (bid < 576) {
        __shared__ float tile[64][65];
        int b = bid / 288, rem = bid % 288;
        int nt = rem / 8, cb = rem % 8;
        int n0 = nt * 64, c0 = cb * 64;
        int tc = t >> 6, tn = t & 63;
#pragma unroll
        for (int i = 0; i < 16; i++) {
            int cl = i * 4 + tc;
            tile[cl][tn] = x[(size_t)(b * CC + c0 + cl) * NN + n0 + tn];
        }
        __syncthreads();
#pragma unroll
        for (int i = 0; i < 16; i++) {
            int nl = i * 4 + tc;
            xT[(size_t)(b * NN + n0 + nl) * CC + c0 + tn] = (__bf16)tile[tn][nl];
        }
    } else {
        int wid = bid - 576;
        int base = wid * 256 + t;
#pragma unroll
        for (int i = 0; i < 16; i++) {
            int j = base + i * 16384;           // covers 262144 = 384*512 + 512*128
            if (j < O3 * CC) wqb[j] = (__bf16)wqkv[j];
            else             wob[j - O3 * CC] = (__bf16)wout[j - O3 * CC];
        }
    }
}

// ---------------------------------------------------------------------------
// Kernel 1: QKV GEMM  qkvT[n,o] = sum_c xT[n,c] * W[o,c]  (per batch),
//           fused per-head L2 norm of q,k.  Outputs (fp16 for k2's f16 MFMA):
//           Q,K: [bh][n][16] f16 ;  VT: [bh][16][n] f16
// ---------------------------------------------------------------------------
__global__ __launch_bounds__(256) void k1_qkv(
    const __bf16* __restrict__ xT, const __bf16* __restrict__ wqb,
    _Float16* __restrict__ Q, _Float16* __restrict__ K, _Float16* __restrict__ VT)
{
    int ob = blockIdx.x, nt = blockIdx.y, b = blockIdx.z;
    int lane = threadIdx.x & 63, wave = threadIdx.x >> 6;
    int quad = lane >> 4, col = lane & 15;
    int n0 = nt * 64 + wave * 16;
    int o0 = ob * 32;

    f32x4 acc[2];
    acc[0] = (f32x4){0.f, 0.f, 0.f, 0.f};
    acc[1] = (f32x4){0.f, 0.f, 0.f, 0.f};

    const __bf16* arow = xT + (size_t)(b * NN + n0 + col) * CC + quad * 8;
    const __bf16* brow0 = wqb + (size_t)(o0 + col) * CC + quad * 8;
    const __bf16* brow1 = brow0 + 16 * CC;

    bf16x8 a  = *(const bf16x8*)(arow);
    bf16x8 w0 = *(const bf16x8*)(brow0);
    bf16x8 w1 = *(const bf16x8*)(brow1);
#pragma unroll
    for (int ks = 0; ks < 16; ks++) {
        bf16x8 an, wn0, wn1;
        if (ks < 15) {
            an  = *(const bf16x8*)(arow + (ks + 1) * 32);
            wn0 = *(const bf16x8*)(brow0 + (ks + 1) * 32);
            wn1 = *(const bf16x8*)(brow1 + (ks + 1) * 32);
        }
        acc[0] = __builtin_amdgcn_mfma_f32_16x16x32_bf16(a, w0, acc[0], 0, 0, 0);
        acc[1] = __builtin_amdgcn_mfma_f32_16x16x32_bf16(a, w1, acc[1], 0, 0, 0);
        a = an; w0 = wn0; w1 = wn1;
    }

#pragma unroll
    for (int s = 0; s < 2; s++) {
        int oc = o0 + s * 16 + col;
        int d = oc & 15, h = (oc >> 4) & 7, kind = oc >> 7;  // 0=q 1=k 2=v
        f32x4 v = acc[s];
        if (kind < 2) {
            float ss0 = v[0] * v[0], ss1 = v[1] * v[1], ss2 = v[2] * v[2], ss3 = v[3] * v[3];
#pragma unroll
            for (int m = 1; m < 16; m <<= 1) {
                ss0 += __shfl_xor(ss0, m);
                ss1 += __shfl_xor(ss1, m);
                ss2 += __shfl_xor(ss2, m);
                ss3 += __shfl_xor(ss3, m);
            }
            v[0] *= 1.0f / fmaxf(sqrtf(ss0), 1e-12f);
            v[1] *= 1.0f / fmaxf(sqrtf(ss1), 1e-12f);
            v[2] *= 1.0f / fmaxf(sqrtf(ss2), 1e-12f);
            v[3] *= 1.0f / fmaxf(sqrtf(ss3), 1e-12f);
            _Float16* dst = (kind == 0 ? Q : K) + (size_t)(b * NH + h) * NN * DD;
#pragma unroll
            for (int r = 0; r < 4; r++) {
                int n = n0 + quad * 4 + r;
                dst[(size_t)n * DD + d] = (_Float16)v[r];
            }
        } else {
            f16x4 pk;
#pragma unroll
            for (int r = 0; r < 4; r++) pk[r] = (_Float16)v[r];
            int n = n0 + quad * 4;
            *(f16x4*)(VT + (size_t)((b * NH + h) * DD + d) * NN + n) = pk;
        }
    }
}

// ---------------------------------------------------------------------------
// Kernel 2: attention — transpose-free flash via K=16 MFMAs, now with
// 4x REGISTER Q-BLOCKING (64 q-rows per wave): one K/V chunk load feeds 4
// independent SxT->exp->PV streams (4x ILP, 4x fewer loads per unit work).
// 8-way split-K over keys (288 each); partials combined via fp32 atomicAdd
// into a single buffer (memset to 0 mid-stream). All fragments are NAMED
// registers (runtime-indexed local arrays scratch-demote: round-5 lesson).
//   S^T = mfma(A=K-frag, B=Q-frag): lane(quad,col) = S^T[key=quad*4+r][q=col]
//   exp2 in place -> same regs are the B-operand for O^T += mfma(A=V^T, B=P).
// Outputs (atomic-accumulated): Opart[bh][d][n] fp32 ; Lpart[bh][n] fp32
// ---------------------------------------------------------------------------
__global__ __launch_bounds__(256) void k2_attn(
    const _Float16* __restrict__ Q, const _Float16* __restrict__ K,
    const _Float16* __restrict__ VT, const float* __restrict__ temp,
    float* __restrict__ Opart, float* __restrict__ Lpart)
{
    int qt = blockIdx.x, bh = blockIdx.y, sp = blockIdx.z;
    int lane = threadIdx.x & 63, wave = threadIdx.x >> 6;
    int quad = lane >> 4, col = lane & 15;
    int kbase = sp * 288;                 // 8 splits x 288 keys = 18 chunks of 16
    int qbase = qt * 256 + wave * 64;     // this wave's 64 q-rows

    const _Float16* Qb = Q + (size_t)bh * NN * DD;
    float tl2 = temp[bh & 7] * 1.4426950408889634f;   // exp(x)=2^(x*log2e)

    // 4 Q B-fragments: Q[q=qbase+f*16+col][d=quad*4..+3]
    f16x4 qf0 = *(const f16x4*)(Qb + (size_t)(qbase +  0 + col) * DD + quad * 4);
    f16x4 qf1 = *(const f16x4*)(Qb + (size_t)(qbase + 16 + col) * DD + quad * 4);
    f16x4 qf2 = *(const f16x4*)(Qb + (size_t)(qbase + 32 + col) * DD + quad * 4);
    f16x4 qf3 = *(const f16x4*)(Qb + (size_t)(qbase + 48 + col) * DD + quad * 4);

    f32x4 oa0 = {0.f,0.f,0.f,0.f}, oa1 = {0.f,0.f,0.f,0.f};
    f32x4 oa2 = {0.f,0.f,0.f,0.f}, oa3 = {0.f,0.f,0.f,0.f};
    float la0 = 0.f, la1 = 0.f, la2 = 0.f, la3 = 0.f;
    const f32x4 zc = {0.f,0.f,0.f,0.f};

    // K A-frag chunk: K[key=ch+col][d=quad*4..+3]   (contiguous 512B/wave)
    // V A-frag chunk: VT[d=col][key=ch+quad*4..+3]
    const _Float16* kp = K + (size_t)bh * NN * DD + (size_t)(kbase + col) * DD + quad * 4;
    const _Float16* vp = VT + (size_t)bh * DD * NN + (size_t)col * NN + kbase + quad * 4;

    f16x4 kfa = *(const f16x4*)(kp);
    f16x4 kfb = *(const f16x4*)(kp + 16 * DD);
    f16x4 vfa = *(const f16x4*)(vp);
    f16x4 vfb = *(const f16x4*)(vp + 16);

#define K2_CHUNK(KF, VF)                                                        \
    {                                                                           \
        f32x4 s0 = __builtin_amdgcn_mfma_f32_16x16x16f16(KF, qf0, zc, 0, 0, 0); \
        f32x4 s1 = __builtin_amdgcn_mfma_f32_16x16x16f16(KF, qf1, zc, 0, 0, 0); \
        f32x4 s2 = __builtin_amdgcn_mfma_f32_16x16x16f16(KF, qf2, zc, 0, 0, 0); \
        f32x4 s3 = __builtin_amdgcn_mfma_f32_16x16x16f16(KF, qf3, zc, 0, 0, 0); \
        f16x4 p0, p1, p2, p3;                                                   \
        _Pragma("unroll")                                                       \
        for (int r = 0; r < 4; ++r) {                                           \
            float e0 = __builtin_amdgcn_exp2f(tl2 * s0[r]);                     \
            float e1 = __builtin_amdgcn_exp2f(tl2 * s1[r]);                     \
            float e2 = __builtin_amdgcn_exp2f(tl2 * s2[r]);                     \
            float e3 = __builtin_amdgcn_exp2f(tl2 * s3[r]);                     \
            p0[r] = (_Float16)e0; la0 += e0;                                    \
            p1[r] = (_Float16)e1; la1 += e1;                                    \
            p2[r] = (_Float16)e2; la2 += e2;                                    \
            p3[r] = (_Float16)e3; la3 += e3;                                    \
        }                                                                       \
        oa0 = __builtin_amdgcn_mfma_f32_16x16x16f16(VF, p0, oa0, 0, 0, 0);      \
        oa1 = __builtin_amdgcn_mfma_f32_16x16x16f16(VF, p1, oa1, 0, 0, 0);      \
        oa2 = __builtin_amdgcn_mfma_f32_16x16x16f16(VF, p2, oa2, 0, 0, 0);      \
        oa3 = __builtin_amdgcn_mfma_f32_16x16x16f16(VF, p3, oa3, 0, 0, 0);      \
    }

    for (int g = 0; g < 9; ++g) {        // 9 groups x 32 keys = 288
        f16x4 kna, knb, vna, vnb;
        if (g < 8) {
            kna = *(const f16x4*)(kp + 32 * DD);
            knb = *(const f16x4*)(kp + 48 * DD);
            vna = *(const f16x4*)(vp + 32);
            vnb = *(const f16x4*)(vp + 48);
        }
        K2_CHUNK(kfa, vfa)
        K2_CHUNK(kfb, vfb)
        kfa = kna; kfb = knb; vfa = vna; vfb = vnb;
        kp += 32 * DD; vp += 32;
    }
#undef K2_CHUNK

    // reduce l across quads (per q-frag): after this every lane holds l[q=col]
    la0 += __shfl_xor(la0, 16); la0 += __shfl_xor(la0, 32);
    la1 += __shfl_xor(la1, 16); la1 += __shfl_xor(la1, 32);
    la2 += __shfl_xor(la2, 16); la2 += __shfl_xor(la2, 32);
    la3 += __shfl_xor(la3, 16); la3 += __shfl_xor(la3, 32);

    // O^T[d=quad*4+r][q=qbase+f*16+col] -> atomicAdd into Opart[bh][d][n]
    float* Ob = Opart + ((size_t)bh * DD + quad * 4) * NN + qbase + col;
#pragma unroll
    for (int r = 0; r < 4; ++r) {
        atomicAdd(Ob + (size_t)r * NN +  0, oa0[r]);
        atomicAdd(Ob + (size_t)r * NN + 16, oa1[r]);
        atomicAdd(Ob + (size_t)r * NN + 32, oa2[r]);
        atomicAdd(Ob + (size_t)r * NN + 48, oa3[r]);
    }
    // each lane contributes the l of q-frag f==quad at n = qbase+quad*16+col
    float lv = (quad == 0) ? la0 : (quad == 1) ? la1 : (quad == 2) ? la2 : la3;
    atomicAdd(Lpart + (size_t)bh * NN + qbase + quad * 16 + col, lv);
}

// ---------------------------------------------------------------------------
// Kernel 2c: divide by l, write AO: [b][n][t=h*16+d] bf16. One thread/(bh,n).
// ---------------------------------------------------------------------------
__global__ __launch_bounds__(256) void k2c_combine(
    const float* __restrict__ Opart, const float* __restrict__ Lpart,
    __bf16* __restrict__ AO)
{
    int gid = blockIdx.x * 256 + threadIdx.x;   // 0..36863
    int bh = gid / NN, n = gid % NN;
    int b = bh >> 3, h = bh & 7;
    const float* O0 = Opart + (size_t)bh * DD * NN + n;
    float inv = 1.0f / Lpart[(size_t)bh * NN + n];
    bf16x8 v0, v1;
#pragma unroll
    for (int d = 0; d < 8; d++)
        v0[d] = (__bf16)(O0[(size_t)d * NN] * inv);
#pragma unroll
    for (int d = 8; d < 16; d++)
        v1[d - 8] = (__bf16)(O0[(size_t)d * NN] * inv);
    __bf16* dst = AO + (size_t)b * NN * TT + (size_t)n * TT + h * DD;
    *(bf16x8*)dst = v0;
    *(bf16x8*)(dst + 8) = v1;
}

// ---------------------------------------------------------------------------
// Kernel 3: projection  out[b,c,n] = sum_t w_out[c,t] * AO[b,n,t]  (pre-BN fp32
// straight into d_out). c-slab 32 per wave: grid (16,36,2)=1152 blocks.
// ---------------------------------------------------------------------------
__global__ __launch_bounds__(256) void k3_proj(
    const __bf16* __restrict__ AO, const __bf16* __restrict__ wob,
    float* __restrict__ out)
{
    int cb = blockIdx.x, nt = blockIdx.y, b = blockIdx.z;
    int lane = threadIdx.x & 63, wave = threadIdx.x >> 6;
    int quad = lane >> 4, col = lane & 15;
    int n0 = nt * 64 + wave * 16, c0 = cb * 32;

    f32x4 acc[2];
    acc[0] = (f32x4){0.f, 0.f, 0.f, 0.f};
    acc[1] = (f32x4){0.f, 0.f, 0.f, 0.f};

    const __bf16* ab = AO + (size_t)(b * NN + n0 + col) * TT + quad * 8;
    const __bf16* wb0 = wob + (size_t)(c0 + col) * TT + quad * 8;
    const __bf16* wb1 = wb0 + 16 * TT;
#pragma unroll
    for (int ks = 0; ks < 4; ks++) {
        bf16x8 a  = *(const bf16x8*)(ab + ks * 32);
        bf16x8 w0 = *(const bf16x8*)(wb0 + ks * 32);
        bf16x8 w1 = *(const bf16x8*)(wb1 + ks * 32);
        acc[0] = __builtin_amdgcn_mfma_f32_16x16x32_bf16(a, w0, acc[0], 0, 0, 0);
        acc[1] = __builtin_amdgcn_mfma_f32_16x16x32_bf16(a, w1, acc[1], 0, 0, 0);
    }
#pragma unroll
    for (int s = 0; s < 2; s++) {
        int c = c0 + s * 16 + col;
        float* dst = out + (size_t)(b * CC + c) * NN + n0 + quad * 4;
        *(f32x4*)dst = acc[s];
    }
}

// ---------------------------------------------------------------------------
// Kernel 4: training-mode BatchNorm, in place on d_out. One block per channel.
// ---------------------------------------------------------------------------
__global__ __launch_bounds__(256) void k4_bn(
    float* __restrict__ out, const float* __restrict__ gamma,
    const float* __restrict__ beta)
{
    int c = blockIdx.x;
    int t = threadIdx.x;
    float vals[18];
    float s = 0.f, q = 0.f;
#pragma unroll
    for (int i = 0; i < 18; i++) {
        int j = i * 256 + t;          // 0..4607 over (b,n)
        int b = j / NN, n = j % NN;
        float v = out[(size_t)(b * CC + c) * NN + n];
        vals[i] = v; s += v; q += v * v;
    }
#pragma unroll
    for (int m = 1; m < 64; m <<= 1) { s += __shfl_xor(s, m); q += __shfl_xor(q, m); }
    __shared__ float rs[4], rq[4];
    int lane = t & 63, wave = t >> 6;
    if (lane == 0) { rs[wave] = s; rq[wave] = q; }
    __syncthreads();
    s = rs[0] + rs[1] + rs[2] + rs[3];
    q = rq[0] + rq[1] + rq[2] + rq[3];
    float mean = s * (1.0f / 4608.0f);
    float var = q * (1.0f / 4608.0f) - mean * mean;
    float sc = rsqrtf(var + 1e-5f) * gamma[c];
    float sh = beta[c] - mean * sc;
#pragma unroll
    for (int i = 0; i < 18; i++) {
        int j = i * 256 + t;
        int b = j / NN, n = j % NN;
        out[(size_t)(b * CC + c) * NN + n] = vals[i] * sc + sh;
    }
}

// ---------------------------------------------------------------------------
extern "C" void kernel_launch(void* const* d_in, const int* in_sizes, int n_in,
                              void* d_out, int out_size, void* d_ws, size_t ws_size,
                              hipStream_t stream) {
    const float* x     = (const float*)d_in[0];
    const float* wqkv  = (const float*)d_in[1];
    const float* temp  = (const float*)d_in[2];
    const float* wout  = (const float*)d_in[3];
    const float* gamma = (const float*)d_in[4];
    const float* beta  = (const float*)d_in[5];
    float* out = (float*)d_out;

    char* ws = (char*)d_ws;
    // workspace layout (bytes). xT/wqb are DEAD after k1 -> region [0,5.11MB)
    // is reused for the k2 atomic partials (memset AFTER k1, stream-ordered).
    const size_t OFF_XT = 0;                 // 2*2304*512*2   = 4,718,592
    const size_t OFF_WQ = 4718592;           // 384*512*2      =   393,216
    const size_t OFF_WO = 5111808;           // 512*128*2      =   131,072
    const size_t OFF_Q  = 5242880;           // 2*8*2304*16*2  = 1,179,648
    const size_t OFF_K  = 6422528;
    const size_t OFF_VT = 7602176;
    const size_t OFF_AO = 8781824;           // 2*2304*128*2   = 1,179,648 -> end 9,961,472
    const size_t OFF_OP = 0;                 // 16*16*2304*4   = 2,359,296 (aliases xT)
    const size_t OFF_LP = 4718592;           // 16*2304*4      =   147,456 (aliases wqb)

    __bf16* xT  = (__bf16*)(ws + OFF_XT);
    __bf16* wqb = (__bf16*)(ws + OFF_WQ);
    __bf16* wob = (__bf16*)(ws + OFF_WO);
    _Float16* Q  = (_Float16*)(ws + OFF_Q);
    _Float16* K  = (_Float16*)(ws + OFF_K);
    _Float16* VT = (_Float16*)(ws + OFF_VT);
    __bf16* AO  = (__bf16*)(ws + OFF_AO);
    float* Opart = (float*)(ws + OFF_OP);
    float* Lpart = (float*)(ws + OFF_LP);

    k0_convert<<<640, 256, 0, stream>>>(x, wqkv, wout, xT, wqb, wob);
    k1_qkv<<<dim3(12, 36, 2), 256, 0, stream>>>(xT, wqb, Q, K, VT);
    hipMemsetAsync(ws + OFF_OP, 0, 16 * DD * NN * sizeof(float), stream);
    hipMemsetAsync(ws + OFF_LP, 0, 16 * NN * sizeof(float), stream);
    k2_attn<<<dim3(9, 16, 8), 256, 0, stream>>>(Q, K, VT, temp, Opart, Lpart);
    k2c_combine<<<144, 256, 0, stream>>>(Opart, Lpart, AO);
    k3_proj<<<dim3(16, 36, 2), 256, 0, stream>>>(AO, wob, out);
    k4_bn<<<512, 256, 0, stream>>>(out, gamma, beta);
}

// Round 8
// 141.850 us; speedup vs baseline: 2.6776x; 1.0601x over previous
//
#include <hip/hip_runtime.h>

// Problem constants
#define NB 2
#define CC 512
#define NN 2304
#define NH 8
#define DD 16
#define TT 128          // NH*DD
#define O3 384          // 3*TT

typedef __attribute__((ext_vector_type(4))) float f32x4;
typedef __attribute__((ext_vector_type(8))) __bf16 bf16x8;
typedef __attribute__((ext_vector_type(4))) __bf16 bf16x4;
typedef __attribute__((ext_vector_type(4))) _Float16 f16x4;

// ---------------------------------------------------------------------------
// Kernel 0: convert x [b,c,n] fp32 -> xT [b,n,c] bf16 (LDS tile transpose),
//           plus straight fp32->bf16 conversion of w_qkv and w_out.
// ---------------------------------------------------------------------------
__global__ __launch_bounds__(256) void k0_convert(
    const float* __restrict__ x, const float* __restrict__ wqkv,
    const float* __restrict__ wout,
    __bf16* __restrict__ xT, __bf16* __restrict__ wqb, __bf16* __restrict__ wob)
{
    int bid = blockIdx.x;
    int t = threadIdx.x;
    if (bid < 576) {
        __shared__ float tile[64][65];
        int b = bid / 288, rem = bid % 288;
        int nt = rem / 8, cb = rem % 8;
        int n0 = nt * 64, c0 = cb * 64;
        int tc = t >> 6, tn = t & 63;
#pragma unroll
        for (int i = 0; i < 16; i++) {
            int cl = i * 4 + tc;
            tile[cl][tn] = x[(size_t)(b * CC + c0 + cl) * NN + n0 + tn];
        }
        __syncthreads();
#pragma unroll
        for (int i = 0; i < 16; i++) {
            int nl = i * 4 + tc;
            xT[(size_t)(b * NN + n0 + nl) * CC + c0 + tn] = (__bf16)tile[tn][nl];
        }
    } else {
        int wid = bid - 576;
        int base = wid * 256 + t;
#pragma unroll
        for (int i = 0; i < 16; i++) {
            int j = base + i * 16384;           // covers 262144 = 384*512 + 512*128
            if (j < O3 * CC) wqb[j] = (__bf16)wqkv[j];
            else             wob[j - O3 * CC] = (__bf16)wout[j - O3 * CC];
        }
    }
}

// ---------------------------------------------------------------------------
// Kernel 1: QKV GEMM  qkvT[n,o] = sum_c xT[n,c] * W[o,c]  (per batch),
//           fused per-head L2 norm of q,k.  Outputs (fp16 for k2's f16 MFMA):
//           Q,K: [bh][n][16] f16 ;  VT: [bh][16][n] f16
// ---------------------------------------------------------------------------
__global__ __launch_bounds__(256) void k1_qkv(
    const __bf16* __restrict__ xT, const __bf16* __restrict__ wqb,
    _Float16* __restrict__ Q, _Float16* __restrict__ K, _Float16* __restrict__ VT)
{
    int ob = blockIdx.x, nt = blockIdx.y, b = blockIdx.z;
    int lane = threadIdx.x & 63, wave = threadIdx.x >> 6;
    int quad = lane >> 4, col = lane & 15;
    int n0 = nt * 64 + wave * 16;
    int o0 = ob * 32;

    f32x4 acc[2];
    acc[0] = (f32x4){0.f, 0.f, 0.f, 0.f};
    acc[1] = (f32x4){0.f, 0.f, 0.f, 0.f};

    const __bf16* arow = xT + (size_t)(b * NN + n0 + col) * CC + quad * 8;
    const __bf16* brow0 = wqb + (size_t)(o0 + col) * CC + quad * 8;
    const __bf16* brow1 = brow0 + 16 * CC;

    bf16x8 a  = *(const bf16x8*)(arow);
    bf16x8 w0 = *(const bf16x8*)(brow0);
    bf16x8 w1 = *(const bf16x8*)(brow1);
#pragma unroll
    for (int ks = 0; ks < 16; ks++) {
        bf16x8 an, wn0, wn1;
        if (ks < 15) {
            an  = *(const bf16x8*)(arow + (ks + 1) * 32);
            wn0 = *(const bf16x8*)(brow0 + (ks + 1) * 32);
            wn1 = *(const bf16x8*)(brow1 + (ks + 1) * 32);
        }
        acc[0] = __builtin_amdgcn_mfma_f32_16x16x32_bf16(a, w0, acc[0], 0, 0, 0);
        acc[1] = __builtin_amdgcn_mfma_f32_16x16x32_bf16(a, w1, acc[1], 0, 0, 0);
        a = an; w0 = wn0; w1 = wn1;
    }

#pragma unroll
    for (int s = 0; s < 2; s++) {
        int oc = o0 + s * 16 + col;
        int d = oc & 15, h = (oc >> 4) & 7, kind = oc >> 7;  // 0=q 1=k 2=v
        f32x4 v = acc[s];
        if (kind < 2) {
            float ss0 = v[0] * v[0], ss1 = v[1] * v[1], ss2 = v[2] * v[2], ss3 = v[3] * v[3];
#pragma unroll
            for (int m = 1; m < 16; m <<= 1) {
                ss0 += __shfl_xor(ss0, m);
                ss1 += __shfl_xor(ss1, m);
                ss2 += __shfl_xor(ss2, m);
                ss3 += __shfl_xor(ss3, m);
            }
            v[0] *= 1.0f / fmaxf(sqrtf(ss0), 1e-12f);
            v[1] *= 1.0f / fmaxf(sqrtf(ss1), 1e-12f);
            v[2] *= 1.0f / fmaxf(sqrtf(ss2), 1e-12f);
            v[3] *= 1.0f / fmaxf(sqrtf(ss3), 1e-12f);
            _Float16* dst = (kind == 0 ? Q : K) + (size_t)(b * NH + h) * NN * DD;
#pragma unroll
            for (int r = 0; r < 4; r++) {
                int n = n0 + quad * 4 + r;
                dst[(size_t)n * DD + d] = (_Float16)v[r];
            }
        } else {
            f16x4 pk;
#pragma unroll
            for (int r = 0; r < 4; r++) pk[r] = (_Float16)v[r];
            int n = n0 + quad * 4;
            *(f16x4*)(VT + (size_t)((b * NH + h) * DD + d) * NN + n) = pk;
        }
    }
}

// ---------------------------------------------------------------------------
// Kernel 2: attention — transpose-free flash via K=16 MFMAs with 4x register
// Q-blocking (64 q-rows per wave). 8-way split-K over keys (288 each).
// ROUND-8 CHANGE: partials DIRECT-STORED per split (no atomics, no memsets;
// R7's ~5M device-scope atomicAdd lane-ops were the combine bottleneck).
//   S^T = mfma(A=K-frag, B=Q-frag): lane(quad,col) = S^T[key=quad*4+r][q=col]
//   exp2 in place -> same regs are the B-operand for O^T += mfma(A=V^T, B=P).
// All fragments NAMED registers (runtime-indexed arrays scratch-demote: R5).
// Outputs: Opart[sp][bh][d][n] fp32 ; Lpart[sp][bh][n] fp32
// ---------------------------------------------------------------------------
__global__ __launch_bounds__(256) void k2_attn(
    const _Float16* __restrict__ Q, const _Float16* __restrict__ K,
    const _Float16* __restrict__ VT, const float* __restrict__ temp,
    float* __restrict__ Opart, float* __restrict__ Lpart)
{
    int qt = blockIdx.x, bh = blockIdx.y, sp = blockIdx.z;
    int lane = threadIdx.x & 63, wave = threadIdx.x >> 6;
    int quad = lane >> 4, col = lane & 15;
    int kbase = sp * 288;                 // 8 splits x 288 keys = 18 chunks of 16
    int qbase = qt * 256 + wave * 64;     // this wave's 64 q-rows

    const _Float16* Qb = Q + (size_t)bh * NN * DD;
    float tl2 = temp[bh & 7] * 1.4426950408889634f;   // exp(x)=2^(x*log2e)

    // 4 Q B-fragments: Q[q=qbase+f*16+col][d=quad*4..+3]
    f16x4 qf0 = *(const f16x4*)(Qb + (size_t)(qbase +  0 + col) * DD + quad * 4);
    f16x4 qf1 = *(const f16x4*)(Qb + (size_t)(qbase + 16 + col) * DD + quad * 4);
    f16x4 qf2 = *(const f16x4*)(Qb + (size_t)(qbase + 32 + col) * DD + quad * 4);
    f16x4 qf3 = *(const f16x4*)(Qb + (size_t)(qbase + 48 + col) * DD + quad * 4);

    f32x4 oa0 = {0.f,0.f,0.f,0.f}, oa1 = {0.f,0.f,0.f,0.f};
    f32x4 oa2 = {0.f,0.f,0.f,0.f}, oa3 = {0.f,0.f,0.f,0.f};
    float la0 = 0.f, la1 = 0.f, la2 = 0.f, la3 = 0.f;
    const f32x4 zc = {0.f,0.f,0.f,0.f};

    // K A-frag chunk: K[key=ch+col][d=quad*4..+3]   (contiguous 512B/wave)
    // V A-frag chunk: VT[d=col][key=ch+quad*4..+3]
    const _Float16* kp = K + (size_t)bh * NN * DD + (size_t)(kbase + col) * DD + quad * 4;
    const _Float16* vp = VT + (size_t)bh * DD * NN + (size_t)col * NN + kbase + quad * 4;

    f16x4 kfa = *(const f16x4*)(kp);
    f16x4 kfb = *(const f16x4*)(kp + 16 * DD);
    f16x4 vfa = *(const f16x4*)(vp);
    f16x4 vfb = *(const f16x4*)(vp + 16);

#define K2_CHUNK(KF, VF)                                                        \
    {                                                                           \
        f32x4 s0 = __builtin_amdgcn_mfma_f32_16x16x16f16(KF, qf0, zc, 0, 0, 0); \
        f32x4 s1 = __builtin_amdgcn_mfma_f32_16x16x16f16(KF, qf1, zc, 0, 0, 0); \
        f32x4 s2 = __builtin_amdgcn_mfma_f32_16x16x16f16(KF, qf2, zc, 0, 0, 0); \
        f32x4 s3 = __builtin_amdgcn_mfma_f32_16x16x16f16(KF, qf3, zc, 0, 0, 0); \
        f16x4 p0, p1, p2, p3;                                                   \
        _Pragma("unroll")                                                       \
        for (int r = 0; r < 4; ++r) {                                           \
            float e0 = __builtin_amdgcn_exp2f(tl2 * s0[r]);                     \
            float e1 = __builtin_amdgcn_exp2f(tl2 * s1[r]);                     \
            float e2 = __builtin_amdgcn_exp2f(tl2 * s2[r]);                     \
            float e3 = __builtin_amdgcn_exp2f(tl2 * s3[r]);                     \
            p0[r] = (_Float16)e0; la0 += e0;                                    \
            p1[r] = (_Float16)e1; la1 += e1;                                    \
            p2[r] = (_Float16)e2; la2 += e2;                                    \
            p3[r] = (_Float16)e3; la3 += e3;                                    \
        }                                                                       \
        oa0 = __builtin_amdgcn_mfma_f32_16x16x16f16(VF, p0, oa0, 0, 0, 0);      \
        oa1 = __builtin_amdgcn_mfma_f32_16x16x16f16(VF, p1, oa1, 0, 0, 0);      \
        oa2 = __builtin_amdgcn_mfma_f32_16x16x16f16(VF, p2, oa2, 0, 0, 0);      \
        oa3 = __builtin_amdgcn_mfma_f32_16x16x16f16(VF, p3, oa3, 0, 0, 0);      \
    }

    for (int g = 0; g < 9; ++g) {        // 9 groups x 32 keys = 288
        f16x4 kna, knb, vna, vnb;
        if (g < 8) {
            kna = *(const f16x4*)(kp + 32 * DD);
            knb = *(const f16x4*)(kp + 48 * DD);
            vna = *(const f16x4*)(vp + 32);
            vnb = *(const f16x4*)(vp + 48);
        }
        K2_CHUNK(kfa, vfa)
        K2_CHUNK(kfb, vfb)
        kfa = kna; kfb = knb; vfa = vna; vfb = vnb;
        kp += 32 * DD; vp += 32;
    }
#undef K2_CHUNK

    // reduce l across quads (per q-frag): after this every lane holds l[q=col]
    la0 += __shfl_xor(la0, 16); la0 += __shfl_xor(la0, 32);
    la1 += __shfl_xor(la1, 16); la1 += __shfl_xor(la1, 32);
    la2 += __shfl_xor(la2, 16); la2 += __shfl_xor(la2, 32);
    la3 += __shfl_xor(la3, 16); la3 += __shfl_xor(la3, 32);

    // O^T[d=quad*4+r][q=qbase+f*16+col] -> Opart[sp][bh][d][n] (plain stores)
    float* Ob = Opart + (((size_t)sp * 16 + bh) * DD + quad * 4) * NN + qbase + col;
#pragma unroll
    for (int r = 0; r < 4; ++r) {
        Ob[(size_t)r * NN +  0] = oa0[r];
        Ob[(size_t)r * NN + 16] = oa1[r];
        Ob[(size_t)r * NN + 32] = oa2[r];
        Ob[(size_t)r * NN + 48] = oa3[r];
    }
    // each lane stores the l of q-frag f==quad at n = qbase+quad*16+col
    float lv = (quad == 0) ? la0 : (quad == 1) ? la1 : (quad == 2) ? la2 : la3;
    Lpart[((size_t)sp * 16 + bh) * NN + qbase + quad * 16 + col] = lv;
}

// ---------------------------------------------------------------------------
// Kernel 2c: sum the 8 split partials + divide by l, write AO.
// AO: [b][n][t=h*16+d] bf16. One thread per (bh, n). All loads coalesced.
// ---------------------------------------------------------------------------
__global__ __launch_bounds__(256) void k2c_combine(
    const float* __restrict__ Opart, const float* __restrict__ Lpart,
    __bf16* __restrict__ AO)
{
    int gid = blockIdx.x * 256 + threadIdx.x;   // 0..36863
    int bh = gid / NN, n = gid % NN;
    int b = bh >> 3, h = bh & 7;
    float l = 0.f;
#pragma unroll
    for (int sp = 0; sp < 8; sp++)
        l += Lpart[((size_t)sp * 16 + bh) * NN + n];
    float inv = 1.0f / l;
    float o[16];
#pragma unroll
    for (int d = 0; d < 16; d++) o[d] = 0.f;
#pragma unroll
    for (int sp = 0; sp < 8; sp++) {
        const float* Ob = Opart + ((size_t)sp * 16 + bh) * DD * NN + n;
#pragma unroll
        for (int d = 0; d < 16; d++) o[d] += Ob[(size_t)d * NN];
    }
    bf16x8 v0, v1;
#pragma unroll
    for (int d = 0; d < 8; d++) v0[d] = (__bf16)(o[d] * inv);
#pragma unroll
    for (int d = 0; d < 8; d++) v1[d] = (__bf16)(o[d + 8] * inv);
    __bf16* dst = AO + (size_t)b * NN * TT + (size_t)n * TT + h * DD;
    *(bf16x8*)dst = v0;
    *(bf16x8*)(dst + 8) = v1;
}

// ---------------------------------------------------------------------------
// Kernel 3: projection  out[b,c,n] = sum_t w_out[c,t] * AO[b,n,t]  (pre-BN fp32
// straight into d_out). c-slab 32 per wave: grid (16,36,2)=1152 blocks.
// ---------------------------------------------------------------------------
__global__ __launch_bounds__(256) void k3_proj(
    const __bf16* __restrict__ AO, const __bf16* __restrict__ wob,
    float* __restrict__ out)
{
    int cb = blockIdx.x, nt = blockIdx.y, b = blockIdx.z;
    int lane = threadIdx.x & 63, wave = threadIdx.x >> 6;
    int quad = lane >> 4, col = lane & 15;
    int n0 = nt * 64 + wave * 16, c0 = cb * 32;

    f32x4 acc[2];
    acc[0] = (f32x4){0.f, 0.f, 0.f, 0.f};
    acc[1] = (f32x4){0.f, 0.f, 0.f, 0.f};

    const __bf16* ab = AO + (size_t)(b * NN + n0 + col) * TT + quad * 8;
    const __bf16* wb0 = wob + (size_t)(c0 + col) * TT + quad * 8;
    const __bf16* wb1 = wb0 + 16 * TT;
#pragma unroll
    for (int ks = 0; ks < 4; ks++) {
        bf16x8 a  = *(const bf16x8*)(ab + ks * 32);
        bf16x8 w0 = *(const bf16x8*)(wb0 + ks * 32);
        bf16x8 w1 = *(const bf16x8*)(wb1 + ks * 32);
        acc[0] = __builtin_amdgcn_mfma_f32_16x16x32_bf16(a, w0, acc[0], 0, 0, 0);
        acc[1] = __builtin_amdgcn_mfma_f32_16x16x32_bf16(a, w1, acc[1], 0, 0, 0);
    }
#pragma unroll
    for (int s = 0; s < 2; s++) {
        int c = c0 + s * 16 + col;
        float* dst = out + (size_t)(b * CC + c) * NN + n0 + quad * 4;
        *(f32x4*)dst = acc[s];
    }
}

// ---------------------------------------------------------------------------
// Kernel 4: training-mode BatchNorm, in place on d_out. One block per channel.
// ---------------------------------------------------------------------------
__global__ __launch_bounds__(256) void k4_bn(
    float* __restrict__ out, const float* __restrict__ gamma,
    const float* __restrict__ beta)
{
    int c = blockIdx.x;
    int t = threadIdx.x;
    float vals[18];
    float s = 0.f, q = 0.f;
#pragma unroll
    for (int i = 0; i < 18; i++) {
        int j = i * 256 + t;          // 0..4607 over (b,n)
        int b = j / NN, n = j % NN;
        float v = out[(size_t)(b * CC + c) * NN + n];
        vals[i] = v; s += v; q += v * v;
    }
#pragma unroll
    for (int m = 1; m < 64; m <<= 1) { s += __shfl_xor(s, m); q += __shfl_xor(q, m); }
    __shared__ float rs[4], rq[4];
    int lane = t & 63, wave = t >> 6;
    if (lane == 0) { rs[wave] = s; rq[wave] = q; }
    __syncthreads();
    s = rs[0] + rs[1] + rs[2] + rs[3];
    q = rq[0] + rq[1] + rq[2] + rq[3];
    float mean = s * (1.0f / 4608.0f);
    float var = q * (1.0f / 4608.0f) - mean * mean;
    float sc = rsqrtf(var + 1e-5f) * gamma[c];
    float sh = beta[c] - mean * sc;
#pragma unroll
    for (int i = 0; i < 18; i++) {
        int j = i * 256 + t;
        int b = j / NN, n = j % NN;
        out[(size_t)(b * CC + c) * NN + n] = vals[i] * sc + sh;
    }
}

// ---------------------------------------------------------------------------
extern "C" void kernel_launch(void* const* d_in, const int* in_sizes, int n_in,
                              void* d_out, int out_size, void* d_ws, size_t ws_size,
                              hipStream_t stream) {
    const float* x     = (const float*)d_in[0];
    const float* wqkv  = (const float*)d_in[1];
    const float* temp  = (const float*)d_in[2];
    const float* wout  = (const float*)d_in[3];
    const float* gamma = (const float*)d_in[4];
    const float* beta  = (const float*)d_in[5];
    float* out = (float*)d_out;

    char* ws = (char*)d_ws;
    // workspace layout (bytes). d_ws is ~256 MiB; partials get their own
    // region (no aliasing, no memset, no atomics).
    const size_t OFF_XT = 0;                 // 2*2304*512*2     = 4,718,592
    const size_t OFF_WQ = 4718592;           // 384*512*2        =   393,216
    const size_t OFF_WO = 5111808;           // 512*128*2        =   131,072
    const size_t OFF_Q  = 5242880;           // 2*8*2304*16*2    = 1,179,648
    const size_t OFF_K  = 6422528;
    const size_t OFF_VT = 7602176;
    const size_t OFF_AO = 8781824;           // 2*2304*128*2     = 1,179,648 -> 9,961,472
    const size_t OFF_OP = 9961472;           // 8*16*16*2304*4   = 18,874,368 -> 28,835,840
    const size_t OFF_LP = 28835840;          // 8*16*2304*4      = 1,179,648 -> 30,015,488

    __bf16* xT  = (__bf16*)(ws + OFF_XT);
    __bf16* wqb = (__bf16*)(ws + OFF_WQ);
    __bf16* wob = (__bf16*)(ws + OFF_WO);
    _Float16* Q  = (_Float16*)(ws + OFF_Q);
    _Float16* K  = (_Float16*)(ws + OFF_K);
    _Float16* VT = (_Float16*)(ws + OFF_VT);
    __bf16* AO  = (__bf16*)(ws + OFF_AO);
    float* Opart = (float*)(ws + OFF_OP);
    float* Lpart = (float*)(ws + OFF_LP);

    k0_convert<<<640, 256, 0, stream>>>(x, wqkv, wout, xT, wqb, wob);
    k1_qkv<<<dim3(12, 36, 2), 256, 0, stream>>>(xT, wqb, Q, K, VT);
    k2_attn<<<dim3(9, 16, 8), 256, 0, stream>>>(Q, K, VT, temp, Opart, Lpart);
    k2c_combine<<<144, 256, 0, stream>>>(Opart, Lpart, AO);
    k3_proj<<<dim3(16, 36, 2), 256, 0, stream>>>(AO, wob, out);
    k4_bn<<<512, 256, 0, stream>>>(out, gamma, beta);
}